// Round 1
// baseline (630.835 us; speedup 1.0000x reference)
//
#include <hip/hip_runtime.h>
#include <hip/hip_bf16.h>

// GapModel: per-env species-masked cosine-kernel^2 energy + segment sum.
// per_row[n] = (1/||ps_n||^2) * sum_m w[s_n,m] * (ps_n . sp[s_n,m])^2
// energy[t] = sum_{n: sid[n]==t} per_row[n]
//
// R3: barrier-free register-streaming MFMA GEMM.
//  - B (support points) pre-converted to bf16 once (fused into scatter kernel),
//    loaded straight global->frag (L2-hot, 256 KB/species).
//  - A loaded global->reg (gathered rows via perm), cvt to bf16 in-flight;
//    same fp32 values feed the exact ||ps||^2 accumulation.
//  - BM=256: one block covers all support points -> A fetched once (205 MB),
//    one atomicAdd per env.
//  - K-loop fully unrolled, immediate load offsets, NO __syncthreads and NO LDS
//    in the loop -> no vmcnt(0) drains; compiler pipelines loads across steps.

constexpr int kNEnv     = 100000;
constexpr int kDPS      = 512;
constexpr int kNSpecies = 4;
constexpr int kNSupport = 256;
constexpr int kCap      = 32768;  // per-species bucket cap; E[count]=25000

constexpr int BN = 128;   // envs per block tile
constexpr int BM = 256;   // support pts per block tile (all of them)
constexpr int BK = 32;    // k chunk (one 16x16x32 MFMA deep)

typedef __attribute__((ext_vector_type(8))) short short8;   // 8 bf16 MFMA A/B frag
typedef __attribute__((ext_vector_type(4))) float f32x4;    // MFMA C/D frag

__device__ __forceinline__ short8 pack_bf16x8(const float4& a, const float4& b) {
  union { short8 v; __hip_bfloat162 h[4]; } u;
  u.h[0] = __float22bfloat162_rn({a.x, a.y});
  u.h[1] = __float22bfloat162_rn({a.z, a.w});
  u.h[2] = __float22bfloat162_rn({b.x, b.y});
  u.h[3] = __float22bfloat162_rn({b.z, b.w});
  return u.v;
}

// ---------------- single-pass species bucket scatter + B fp32->bf16 ----------
__global__ void scatter_convert_kernel(const float* __restrict__ sp,
                                       const int* __restrict__ species,
                                       const int* __restrict__ sid,
                                       int* __restrict__ cnt, int* __restrict__ perm,
                                       int* __restrict__ sidp, short* __restrict__ spb) {
  const int t = threadIdx.x;
  const int b = blockIdx.x;
  // support_points conversion: 4*256*512 = 524288 elems; blocks 0..255 do 8/thread
  if (b < (kNSpecies * kNSupport * kDPS) / (256 * 8)) {
    const int base = (b * 256 + t) * 8;
    const float4 lo = *(const float4*)(sp + base);
    const float4 hi = *(const float4*)(sp + base + 4);
    *(short8*)(spb + base) = pack_bf16x8(lo, hi);
  }
  __shared__ int lcnt[kNSpecies];
  __shared__ int lbase[kNSpecies];
  if (t < kNSpecies) lcnt[t] = 0;
  __syncthreads();
  const int i = b * 256 + t;
  const bool v = i < kNEnv;
  int s = 0, r = 0, g = 0;
  if (v) { s = species[i]; r = atomicAdd(&lcnt[s], 1); g = sid[i]; }
  __syncthreads();
  if (t < kNSpecies) lbase[t] = lcnt[t] ? atomicAdd(&cnt[t], lcnt[t]) : 0;
  __syncthreads();
  if (v) {
    const int d = s * kCap + lbase[s] + r;
    perm[d] = i;
    sidp[d] = g;
  }
}

// ---------------- barrier-free streaming MFMA GEMM + norm + epilogue ---------
__global__ __launch_bounds__(256) void gap_gemm_kernel(
    const float* __restrict__ ps, const short* __restrict__ spb,
    const float* __restrict__ w, const int* __restrict__ cnt,
    const int* __restrict__ perm, const int* __restrict__ sidp,
    float* __restrict__ energy) {
  const int s     = blockIdx.z;
  const int count = min(cnt[s], kCap);
  const int tile0 = blockIdx.x * BN;
  if (tile0 >= count) return;

  __shared__ float red[4][64];
  __shared__ float sqs[BN];

  const int tid  = threadIdx.x;
  const int wv   = tid >> 6;
  const int lane = tid & 63;
  const int l15  = lane & 15;
  const int lq   = lane >> 4;
  // wave tile: 64 envs x 128 m
  const int wv_e = (wv & 1) * 64;
  const int wv_m = (wv >> 1) * 128;

  // per-lane A row pointers (gathered via perm; tail rows clamp -> masked later)
  const float* aptr[4];
  #pragma unroll
  for (int fi = 0; fi < 4; ++fi) {
    const int ge   = tile0 + wv_e + fi * 16 + l15;
    const int arow = perm[s * kCap + (ge < count ? ge : count - 1)];
    aptr[fi] = ps + (size_t)arow * kDPS + lq * 8;
  }
  // per-lane B row pointers (bf16, L2-resident) + epilogue weights
  const short* bptr[8];
  float wgt[8];
  const float* w_s = w + s * kNSupport;
  #pragma unroll
  for (int fj = 0; fj < 8; ++fj) {
    const int m = wv_m + fj * 16 + l15;
    bptr[fj] = spb + ((size_t)s * kNSupport + m) * kDPS + lq * 8;
    wgt[fj]  = w_s[m];
  }

  f32x4 acc[4][8];
  #pragma unroll
  for (int fi = 0; fi < 4; ++fi)
    #pragma unroll
    for (int fj = 0; fj < 8; ++fj) acc[fi][fj] = (f32x4)0.f;
  float sq[4] = {0.f, 0.f, 0.f, 0.f};

  // K-loop: 16 steps, fully unrolled, immediate offsets, no barriers, no LDS.
  #pragma unroll
  for (int k0 = 0; k0 < kDPS; k0 += BK) {
    short8 bf[8];
    #pragma unroll
    for (int fj = 0; fj < 8; ++fj) bf[fj] = *(const short8*)(bptr[fj] + k0);
    #pragma unroll
    for (int fi = 0; fi < 4; ++fi) {
      const float4 lo = *(const float4*)(aptr[fi] + k0);
      const float4 hi = *(const float4*)(aptr[fi] + k0 + 4);
      sq[fi] += lo.x * lo.x + lo.y * lo.y + lo.z * lo.z + lo.w * lo.w
              + hi.x * hi.x + hi.y * hi.y + hi.z * hi.z + hi.w * hi.w;
      const short8 af = pack_bf16x8(lo, hi);
      #pragma unroll
      for (int fj = 0; fj < 8; ++fj)
        acc[fi][fj] = __builtin_amdgcn_mfma_f32_16x16x32_bf16(af, bf[fj], acc[fi][fj], 0, 0, 0);
    }
  }

  // ||ps||^2: waves 0,1 cover every (env,k) exactly once; reduce over lq groups
  if (wv < 2) {
    #pragma unroll
    for (int fi = 0; fi < 4; ++fi) {
      float p = sq[fi];
      p += __shfl_xor(p, 16, 64);
      p += __shfl_xor(p, 32, 64);
      if (lane < 16) sqs[wv_e + fi * 16 + lane] = p;
    }
  }

  // epilogue: contrib_env = sum_m w_m * C[env][m]^2
  // C/D layout: col(m) = lane&15, row(env) = (lane>>4)*4 + reg
  #pragma unroll
  for (int fi = 0; fi < 4; ++fi) {
    #pragma unroll
    for (int r = 0; r < 4; ++r) {
      float p = 0.f;
      #pragma unroll
      for (int fj = 0; fj < 8; ++fj) {
        const float c = acc[fi][fj][r];
        p += c * c * wgt[fj];
      }
      p += __shfl_xor(p, 1, 64);
      p += __shfl_xor(p, 2, 64);
      p += __shfl_xor(p, 4, 64);
      p += __shfl_xor(p, 8, 64);
      if (l15 == 0) red[wv][fi * 16 + lq * 4 + r] = p;
    }
  }
  __syncthreads();
  // waves {h, h+2} share env half h; scale by 1/||ps||^2, one atomic per env
  if (tid < BN) {
    const int h  = tid >> 6, el = tid & 63;
    const float v = red[h][el] + red[h + 2][el];
    const int g  = tile0 + h * 64 + el;
    if (g < count) atomicAdd(&energy[sidp[s * kCap + g]], v / sqs[h * 64 + el]);
  }
}

extern "C" void kernel_launch(void* const* d_in, const int* in_sizes, int n_in,
                              void* d_out, int out_size, void* d_ws, size_t ws_size,
                              hipStream_t stream) {
  const float* ps      = (const float*)d_in[0];
  const float* sp      = (const float*)d_in[1];
  const float* w       = (const float*)d_in[2];
  const int*   species = (const int*)d_in[3];
  const int*   sid     = (const int*)d_in[4];
  float* energy = (float*)d_out;

  char* wsb  = (char*)d_ws;
  int*   cnt  = (int*)wsb;                                    // 4 ints (pad 256B)
  int*   perm = (int*)(wsb + 256);                            // 4*kCap ints
  int*   sidp = (int*)(wsb + 256 + 4 * kCap * sizeof(int));   // 4*kCap ints
  short* spb  = (short*)(wsb + 256 + 8 * kCap * sizeof(int)); // bf16 B, 1 MB

  hipMemsetAsync(cnt, 0, 16, stream);
  hipMemsetAsync(energy, 0, out_size * sizeof(float), stream);

  scatter_convert_kernel<<<(kNEnv + 255) / 256, 256, 0, stream>>>(
      sp, species, sid, cnt, perm, sidp, spb);

  dim3 grid(kCap / BN, 1, kNSpecies);  // (256, 1, 4); early-out past count
  gap_gemm_kernel<<<grid, 256, 0, stream>>>(ps, spb, w, cnt, perm, sidp, energy);
}

// Round 2
// 404.966 us; speedup vs baseline: 1.5577x; 1.5577x over previous
//
#include <hip/hip_runtime.h>
#include <hip/hip_bf16.h>

// GapModel: per-env species-masked cosine-kernel^2 energy + segment sum.
// per_row[n] = (1/||ps_n||^2) * sum_m w[s_n,m] * (ps_n . sp[s_n,m])^2
// energy[t] = sum_{n: sid[n]==t} per_row[n]
//
// R4: barrier-free register-streaming MFMA GEMM, spill-free edition.
//  - R3 died of register spills (acc[4][8]=128 VGPRs -> 395 MB scratch WRITE).
//  - Wave tile now 64 envs x 64 m (acc[4][4]=64 VGPRs); the 4 waves of a block
//    share the same 64 envs and cover disjoint 64-m quarters (BM=256 intact:
//    A fetched once from HBM, redundant wave reads hit L1/L2).
//  - B (support points) pre-converted to bf16 once, loaded global->frag.
//  - A global->reg, cvt to bf16 in-flight; fp32 values feed exact ||ps||^2.
//  - K-loop unroll 4 (not 16): enough loads in flight, bounded live ranges.
//  - __launch_bounds__(256,3) caps VGPRs ~170 -> 12 waves/CU.

constexpr int kNEnv     = 100000;
constexpr int kDPS      = 512;
constexpr int kNSpecies = 4;
constexpr int kNSupport = 256;
constexpr int kCap      = 32768;  // per-species bucket cap; E[count]=25000

constexpr int BN = 64;    // envs per block tile (shared by all 4 waves)
constexpr int BK = 32;    // k chunk (one 16x16x32 MFMA deep)

typedef __attribute__((ext_vector_type(8))) short short8;   // 8 bf16 MFMA A/B frag
typedef __attribute__((ext_vector_type(4))) float f32x4;    // MFMA C/D frag

__device__ __forceinline__ short8 pack_bf16x8(const float4& a, const float4& b) {
  union { short8 v; __hip_bfloat162 h[4]; } u;
  u.h[0] = __float22bfloat162_rn({a.x, a.y});
  u.h[1] = __float22bfloat162_rn({a.z, a.w});
  u.h[2] = __float22bfloat162_rn({b.x, b.y});
  u.h[3] = __float22bfloat162_rn({b.z, b.w});
  return u.v;
}

// ---------------- single-pass species bucket scatter + B fp32->bf16 ----------
__global__ void scatter_convert_kernel(const float* __restrict__ sp,
                                       const int* __restrict__ species,
                                       const int* __restrict__ sid,
                                       int* __restrict__ cnt, int* __restrict__ perm,
                                       int* __restrict__ sidp, short* __restrict__ spb) {
  const int t = threadIdx.x;
  const int b = blockIdx.x;
  // support_points conversion: 4*256*512 = 524288 elems; blocks 0..255 do 8/thread
  if (b < (kNSpecies * kNSupport * kDPS) / (256 * 8)) {
    const int base = (b * 256 + t) * 8;
    const float4 lo = *(const float4*)(sp + base);
    const float4 hi = *(const float4*)(sp + base + 4);
    *(short8*)(spb + base) = pack_bf16x8(lo, hi);
  }
  __shared__ int lcnt[kNSpecies];
  __shared__ int lbase[kNSpecies];
  if (t < kNSpecies) lcnt[t] = 0;
  __syncthreads();
  const int i = b * 256 + t;
  const bool v = i < kNEnv;
  int s = 0, r = 0, g = 0;
  if (v) { s = species[i]; r = atomicAdd(&lcnt[s], 1); g = sid[i]; }
  __syncthreads();
  if (t < kNSpecies) lbase[t] = lcnt[t] ? atomicAdd(&cnt[t], lcnt[t]) : 0;
  __syncthreads();
  if (v) {
    const int d = s * kCap + lbase[s] + r;
    perm[d] = i;
    sidp[d] = g;
  }
}

// ---------------- barrier-free streaming MFMA GEMM + norm + epilogue ---------
__global__ __launch_bounds__(256, 3) void gap_gemm_kernel(
    const float* __restrict__ ps, const short* __restrict__ spb,
    const float* __restrict__ w, const int* __restrict__ cnt,
    const int* __restrict__ perm, const int* __restrict__ sidp,
    float* __restrict__ energy) {
  const int s     = blockIdx.z;
  const int count = min(cnt[s], kCap);
  const int tile0 = blockIdx.x * BN;
  if (tile0 >= count) return;

  __shared__ float red[4][64];   // [wave][env] partial contribs
  __shared__ float sqs[BN];      // ||ps||^2 per env

  const int tid  = threadIdx.x;
  const int wv   = tid >> 6;     // wave owns m quarter [wv*64, wv*64+64)
  const int lane = tid & 63;
  const int l15  = lane & 15;
  const int lq   = lane >> 4;

  // per-lane A row pointers (gathered via perm; tail rows clamp -> masked later)
  // all 4 waves read the same 64 envs: HBM once, rest L1/L2 hits
  const float* aptr[4];
  #pragma unroll
  for (int fi = 0; fi < 4; ++fi) {
    const int ge   = tile0 + fi * 16 + l15;
    const int arow = perm[s * kCap + (ge < count ? ge : count - 1)];
    aptr[fi] = ps + (size_t)arow * kDPS + lq * 8;
  }
  // per-lane B row pointers (bf16, L2-resident) + epilogue weights
  const short* bptr[4];
  float wgt[4];
  const float* w_s = w + s * kNSupport;
  #pragma unroll
  for (int fj = 0; fj < 4; ++fj) {
    const int m = wv * 64 + fj * 16 + l15;
    bptr[fj] = spb + ((size_t)s * kNSupport + m) * kDPS + lq * 8;
    wgt[fj]  = w_s[m];
  }

  f32x4 acc[4][4];
  #pragma unroll
  for (int fi = 0; fi < 4; ++fi)
    #pragma unroll
    for (int fj = 0; fj < 4; ++fj) acc[fi][fj] = (f32x4)0.f;
  float sq[4] = {0.f, 0.f, 0.f, 0.f};

  // K-loop: no barriers, no LDS; unroll 4 = ~48 independent loads in window
  #pragma unroll 4
  for (int k0 = 0; k0 < kDPS; k0 += BK) {
    short8 bf[4];
    #pragma unroll
    for (int fj = 0; fj < 4; ++fj) bf[fj] = *(const short8*)(bptr[fj] + k0);
    #pragma unroll
    for (int fi = 0; fi < 4; ++fi) {
      const float4 lo = *(const float4*)(aptr[fi] + k0);
      const float4 hi = *(const float4*)(aptr[fi] + k0 + 4);
      sq[fi] += lo.x * lo.x + lo.y * lo.y + lo.z * lo.z + lo.w * lo.w
              + hi.x * hi.x + hi.y * hi.y + hi.z * hi.z + hi.w * hi.w;
      const short8 af = pack_bf16x8(lo, hi);
      #pragma unroll
      for (int fj = 0; fj < 4; ++fj)
        acc[fi][fj] = __builtin_amdgcn_mfma_f32_16x16x32_bf16(af, bf[fj], acc[fi][fj], 0, 0, 0);
    }
  }

  // ||ps||^2: all waves hold identical sq partials; wave 0 reduces over lq
  if (wv == 0) {
    #pragma unroll
    for (int fi = 0; fi < 4; ++fi) {
      float p = sq[fi];
      p += __shfl_xor(p, 16, 64);
      p += __shfl_xor(p, 32, 64);
      if (lane < 16) sqs[fi * 16 + lane] = p;
    }
  }

  // epilogue: contrib_env = sum_m w_m * C[env][m]^2
  // C/D layout: col(m) = lane&15, row(env) = (lane>>4)*4 + reg
  #pragma unroll
  for (int fi = 0; fi < 4; ++fi) {
    #pragma unroll
    for (int r = 0; r < 4; ++r) {
      float p = 0.f;
      #pragma unroll
      for (int fj = 0; fj < 4; ++fj) {
        const float c = acc[fi][fj][r];
        p += c * c * wgt[fj];
      }
      p += __shfl_xor(p, 1, 64);
      p += __shfl_xor(p, 2, 64);
      p += __shfl_xor(p, 4, 64);
      p += __shfl_xor(p, 8, 64);
      if (l15 == 0) red[wv][fi * 16 + lq * 4 + r] = p;
    }
  }
  __syncthreads();
  // sum the 4 m-quarters, scale by 1/||ps||^2, one atomic per env
  if (tid < BN) {
    const float v = red[0][tid] + red[1][tid] + red[2][tid] + red[3][tid];
    const int g  = tile0 + tid;
    if (g < count) atomicAdd(&energy[sidp[s * kCap + g]], v / sqs[tid]);
  }
}

extern "C" void kernel_launch(void* const* d_in, const int* in_sizes, int n_in,
                              void* d_out, int out_size, void* d_ws, size_t ws_size,
                              hipStream_t stream) {
  const float* ps      = (const float*)d_in[0];
  const float* sp      = (const float*)d_in[1];
  const float* w       = (const float*)d_in[2];
  const int*   species = (const int*)d_in[3];
  const int*   sid     = (const int*)d_in[4];
  float* energy = (float*)d_out;

  char* wsb  = (char*)d_ws;
  int*   cnt  = (int*)wsb;                                    // 4 ints (pad 256B)
  int*   perm = (int*)(wsb + 256);                            // 4*kCap ints
  int*   sidp = (int*)(wsb + 256 + 4 * kCap * sizeof(int));   // 4*kCap ints
  short* spb  = (short*)(wsb + 256 + 8 * kCap * sizeof(int)); // bf16 B, 1 MB

  hipMemsetAsync(cnt, 0, 16, stream);
  hipMemsetAsync(energy, 0, out_size * sizeof(float), stream);

  scatter_convert_kernel<<<(kNEnv + 255) / 256, 256, 0, stream>>>(
      sp, species, sid, cnt, perm, sidp, spb);

  dim3 grid(kCap / BN, 1, kNSpecies);  // (512, 1, 4); early-out past count
  gap_gemm_kernel<<<grid, 256, 0, stream>>>(ps, spb, w, cnt, perm, sidp, energy);
}

// Round 3
// 347.045 us; speedup vs baseline: 1.8177x; 1.1669x over previous
//
#include <hip/hip_runtime.h>
#include <hip/hip_bf16.h>

// GapModel: per-env species-masked cosine-kernel^2 energy + segment sum.
// per_row[n] = (1/||ps_n||^2) * sum_m w[s_n,m] * (ps_n . sp[s_n,m])^2
// energy[t] = sum_{n: sid[n]==t} per_row[n]
//
// R5: block-staged MFMA GEMM (m97-style).
//  - A (gathered fp32 rows) staged once per block into double-buffered LDS via
//    global_load_lds width=16 -> no 4x wave redundancy, no VGPR round-trip.
//  - XOR swizzle (byte ^= (row&7)<<4) applied as: linear LDS dest +
//    pre-swizzled GLOBAL source + swizzled ds_read (rule 21: both-sides).
//  - B (support pts) pre-converted bf16, loaded global->frag (L2-hot).
//  - ||ps||^2 from wave 0's fp32 fragment reads (free during cvt).
//  - One __syncthreads per K-step; its vmcnt(0) drain publishes the stage
//    issued at the TOP of the step -> HBM latency hides under the body.

constexpr int kNEnv     = 100000;
constexpr int kDPS      = 512;
constexpr int kNSpecies = 4;
constexpr int kNSupport = 256;
constexpr int kCap      = 32768;  // per-species bucket cap; E[count]=25000

constexpr int BN = 64;    // envs per block tile
constexpr int BK = 32;    // k chunk per stage (one 16x16x32 MFMA deep)

typedef __attribute__((ext_vector_type(8))) short short8;   // 8 bf16 MFMA A/B frag
typedef __attribute__((ext_vector_type(4))) float f32x4;    // MFMA C/D frag

__device__ __forceinline__ short8 pack_bf16x8(const float4& a, const float4& b) {
  union { short8 v; __hip_bfloat162 h[4]; } u;
  u.h[0] = __float22bfloat162_rn({a.x, a.y});
  u.h[1] = __float22bfloat162_rn({a.z, a.w});
  u.h[2] = __float22bfloat162_rn({b.x, b.y});
  u.h[3] = __float22bfloat162_rn({b.z, b.w});
  return u.v;
}

__device__ __forceinline__ void gload_lds16(const float* g, float* l) {
  __builtin_amdgcn_global_load_lds(
      (const __attribute__((address_space(1))) void*)g,
      (__attribute__((address_space(3))) void*)l, 16, 0, 0);
}

// ---------------- single-pass species bucket scatter + B fp32->bf16 ----------
__global__ void scatter_convert_kernel(const float* __restrict__ sp,
                                       const int* __restrict__ species,
                                       const int* __restrict__ sid,
                                       int* __restrict__ cnt, int* __restrict__ perm,
                                       int* __restrict__ sidp, short* __restrict__ spb) {
  const int t = threadIdx.x;
  const int b = blockIdx.x;
  // support_points conversion: 4*256*512 = 524288 elems; blocks 0..255 do 8/thread
  if (b < (kNSpecies * kNSupport * kDPS) / (256 * 8)) {
    const int base = (b * 256 + t) * 8;
    const float4 lo = *(const float4*)(sp + base);
    const float4 hi = *(const float4*)(sp + base + 4);
    *(short8*)(spb + base) = pack_bf16x8(lo, hi);
  }
  __shared__ int lcnt[kNSpecies];
  __shared__ int lbase[kNSpecies];
  if (t < kNSpecies) lcnt[t] = 0;
  __syncthreads();
  const int i = b * 256 + t;
  const bool v = i < kNEnv;
  int s = 0, r = 0, g = 0;
  if (v) { s = species[i]; r = atomicAdd(&lcnt[s], 1); g = sid[i]; }
  __syncthreads();
  if (t < kNSpecies) lbase[t] = lcnt[t] ? atomicAdd(&cnt[t], lcnt[t]) : 0;
  __syncthreads();
  if (v) {
    const int d = s * kCap + lbase[s] + r;
    perm[d] = i;
    sidp[d] = g;
  }
}

// ---------------- LDS-staged MFMA GEMM + norm + epilogue ---------------------
__global__ __launch_bounds__(256, 3) void gap_gemm_kernel(
    const float* __restrict__ ps, const short* __restrict__ spb,
    const float* __restrict__ w, const int* __restrict__ cnt,
    const int* __restrict__ perm, const int* __restrict__ sidp,
    float* __restrict__ energy) {
  const int s     = blockIdx.z;
  const int count = min(cnt[s], kCap);
  const int tile0 = blockIdx.x * BN;
  if (tile0 >= count) return;

  __shared__ float a_lds[2][BN * BK];   // 2 x 8 KB; rows of 32 fp32 (128 B), swizzled
  __shared__ float red[4][BN];          // per-wave m-quarter partials
  __shared__ float sqs[BN];             // ||ps||^2 per env

  const int tid  = threadIdx.x;
  const int wv   = tid >> 6;            // wave owns m quarter [wv*64, wv*64+64)
  const int lane = tid & 63;
  const int l15  = lane & 15;
  const int lq   = lane >> 4;

  // ---- staging setup: wave wv stages local rows [wv*16, wv*16+16), 2 calls of
  // 8 rows. Lane L -> row c*8 + (L>>3), slot byte (L&7)*16 (LDS linear).
  // Source is pre-swizzled so a swizzled ds_read sees the right data.
  const int sby = (((lane & 7) << 4) ^ ((lane >> 3) << 4));  // src within-row byte
  const float* ssrc[2];
  #pragma unroll
  for (int c = 0; c < 2; ++c) {
    int r  = wv * 16 + c * 8 + (lane >> 3);
    int ge = tile0 + r;
    ge = ge < count ? ge : count - 1;
    ssrc[c] = ps + (size_t)perm[s * kCap + ge] * kDPS + (sby >> 2);
  }
  const int dof0 = (wv * 16) * BK;      // LDS float offsets (wave-uniform)
  const int dof1 = (wv * 16 + 8) * BK;

  // ---- B pointers (bf16, L2-resident) + epilogue weights
  const short* bptr[4];
  float wgt[4];
  const float* w_s = w + s * kNSupport;
  #pragma unroll
  for (int fj = 0; fj < 4; ++fj) {
    const int m = wv * 64 + fj * 16 + l15;
    bptr[fj] = spb + ((size_t)s * kNSupport + m) * kDPS + lq * 8;
    wgt[fj]  = w_s[m];
  }

  // ---- fragment ds_read byte offsets (constant across k): row fi*16+l15,
  // col bytes lq*32 and lq*32+16, each XOR'd with (row&7)<<4 = (l15&7)<<4
  const int fswz = (l15 & 7) << 4;
  const int cb1  = (lq * 32) ^ fswz;
  const int cb2  = (lq * 32 + 16) ^ fswz;
  const int rowb = l15 * 128;

  f32x4 acc[4][4];
  #pragma unroll
  for (int fi = 0; fi < 4; ++fi)
    #pragma unroll
    for (int fj = 0; fj < 4; ++fj) acc[fi][fj] = (f32x4)0.f;
  float sq[4] = {0.f, 0.f, 0.f, 0.f};

#define STAGE(BUF, K0) do {                        \
    gload_lds16(ssrc[0] + (K0), &a_lds[BUF][dof0]); \
    gload_lds16(ssrc[1] + (K0), &a_lds[BUF][dof1]); \
  } while (0)

#define BODY(BUF, K0) do {                                                      \
    short8 bf[4];                                                               \
    _Pragma("unroll")                                                           \
    for (int fj = 0; fj < 4; ++fj) bf[fj] = *(const short8*)(bptr[fj] + (K0));  \
    const char* abase = (const char*)&a_lds[BUF][0];                            \
    _Pragma("unroll")                                                           \
    for (int fi = 0; fi < 4; ++fi) {                                            \
      const float4 f1 = *(const float4*)(abase + fi * 2048 + rowb + cb1);       \
      const float4 f2 = *(const float4*)(abase + fi * 2048 + rowb + cb2);       \
      if (wv == 0)                                                              \
        sq[fi] += f1.x * f1.x + f1.y * f1.y + f1.z * f1.z + f1.w * f1.w         \
                + f2.x * f2.x + f2.y * f2.y + f2.z * f2.z + f2.w * f2.w;        \
      const short8 af = pack_bf16x8(f1, f2);                                    \
      _Pragma("unroll")                                                         \
      for (int fj = 0; fj < 4; ++fj)                                            \
        acc[fi][fj] =                                                           \
            __builtin_amdgcn_mfma_f32_16x16x32_bf16(af, bf[fj], acc[fi][fj], 0, 0, 0); \
    }                                                                           \
  } while (0)

  STAGE(0, 0);
  __syncthreads();  // drains vmcnt(0): buf0 visible to all waves

  #pragma unroll 1
  for (int kp = 0; kp < kDPS; kp += 2 * BK) {
    STAGE(1, kp + BK);           // overlaps with body below
    BODY(0, kp);
    __syncthreads();             // publishes buf1; buf0 reads retired
    if (kp + 2 * BK < kDPS) STAGE(0, kp + 2 * BK);
    BODY(1, kp + BK);
    __syncthreads();             // publishes buf0; buf1 reads retired
  }

#undef STAGE
#undef BODY

  // ||ps||^2: wave 0's lanes covered rows fi*16+l15, k-slices lq*8; sum over lq
  if (wv == 0) {
    #pragma unroll
    for (int fi = 0; fi < 4; ++fi) {
      float p = sq[fi];
      p += __shfl_xor(p, 16, 64);
      p += __shfl_xor(p, 32, 64);
      if (lane < 16) sqs[fi * 16 + lane] = p;
    }
  }

  // epilogue: contrib_env = sum_m w_m * C[env][m]^2
  // C/D layout: col(m) = lane&15, row(env) = (lane>>4)*4 + reg
  #pragma unroll
  for (int fi = 0; fi < 4; ++fi) {
    #pragma unroll
    for (int r = 0; r < 4; ++r) {
      float p = 0.f;
      #pragma unroll
      for (int fj = 0; fj < 4; ++fj) {
        const float c = acc[fi][fj][r];
        p += c * c * wgt[fj];
      }
      p += __shfl_xor(p, 1, 64);
      p += __shfl_xor(p, 2, 64);
      p += __shfl_xor(p, 4, 64);
      p += __shfl_xor(p, 8, 64);
      if (l15 == 0) red[wv][fi * 16 + lq * 4 + r] = p;
    }
  }
  __syncthreads();
  // sum the 4 m-quarters, scale by 1/||ps||^2, one atomic per env
  if (tid < BN) {
    const float v = red[0][tid] + red[1][tid] + red[2][tid] + red[3][tid];
    const int g  = tile0 + tid;
    if (g < count) atomicAdd(&energy[sidp[s * kCap + g]], v / sqs[tid]);
  }
}

extern "C" void kernel_launch(void* const* d_in, const int* in_sizes, int n_in,
                              void* d_out, int out_size, void* d_ws, size_t ws_size,
                              hipStream_t stream) {
  const float* ps      = (const float*)d_in[0];
  const float* sp      = (const float*)d_in[1];
  const float* w       = (const float*)d_in[2];
  const int*   species = (const int*)d_in[3];
  const int*   sid     = (const int*)d_in[4];
  float* energy = (float*)d_out;

  char* wsb  = (char*)d_ws;
  int*   cnt  = (int*)wsb;                                    // 4 ints (pad 256B)
  int*   perm = (int*)(wsb + 256);                            // 4*kCap ints
  int*   sidp = (int*)(wsb + 256 + 4 * kCap * sizeof(int));   // 4*kCap ints
  short* spb  = (short*)(wsb + 256 + 8 * kCap * sizeof(int)); // bf16 B, 1 MB

  hipMemsetAsync(cnt, 0, 16, stream);
  hipMemsetAsync(energy, 0, out_size * sizeof(float), stream);

  scatter_convert_kernel<<<(kNEnv + 255) / 256, 256, 0, stream>>>(
      sp, species, sid, cnt, perm, sidp, spb);

  dim3 grid(kCap / BN, 1, kNSpecies);  // (512, 1, 4); early-out past count
  gap_gemm_kernel<<<grid, 256, 0, stream>>>(ps, spb, w, cnt, perm, sidp, energy);
}